// Round 1
// baseline (361.305 us; speedup 1.0000x reference)
//
#include <hip/hip_runtime.h>
#include <hip/hip_bf16.h>

// MultiHeadAttentionLayer: B=8, S=1024, D_MODEL=1024, H=16, DK=64. fp32 in/out.
// Round 7: (1) GEMM restructured to double-buffered 2-phase (T3-minimum): prefetch of
// K-step t+1 issued BEFORE compute of step t, ONE __syncthreads per step (was 2) so the
// vmcnt drain overlaps 32 MFMAs + frag reads. fp32-A path uses T14 issue-early/write-late
// reg staging. LDS 64KB -> 2 blocks/CU. (2) 1/sqrt(dk) folded into Q-GEMM epilogue
// (cscale) - kills 16 VALU muls/tile in attn. (3) attn: defer-max rescale skip (T13,
// THR=8), tree max/sum reductions, s_setprio around MFMA clusters (T5).
// Buffers: ws[0,8)=W bf16 x4, ws[8,24)=input conv slot (later ao copy), ws[16,32)=vt;
// d_out[0,16)=qh->ao in-place, d_out[16,32)=kh.

#define D_MODEL_ 1024
#define NH_ 16
#define DK_ 64
#define B_ 8
#define S_ 1024
#define M_ (B_ * S_)   // 8192 rows

typedef __hip_bfloat16 bf16;
typedef __attribute__((ext_vector_type(8))) short short8;   // 8 bf16 = 4 VGPRs (MFMA A/B frag)
typedef __attribute__((ext_vector_type(4))) short short4_t; // 4 bf16 = 8B
typedef __attribute__((ext_vector_type(4))) float f32x4;    // MFMA C/D frag

typedef const __attribute__((address_space(1))) unsigned int* gas_u32p;
typedef __attribute__((address_space(3))) unsigned int* las_u32p;

__device__ __forceinline__ short f2bs(float x) {
  bf16 h = __float2bfloat16(x);
  return *reinterpret_cast<short*>(&h);
}

// ---------------- fp32 -> bf16 conversion (memory-bound) ----------------
__global__ __launch_bounds__(256)
void conv_f32_bf16(const float* __restrict__ in, bf16* __restrict__ out) {
  size_t i = ((size_t)blockIdx.x * 256 + threadIdx.x) * 8;
  f32x4 a = *(const f32x4*)(in + i);
  f32x4 b = *(const f32x4*)(in + i + 4);
  short8 s;
  s[0] = f2bs(a[0]); s[1] = f2bs(a[1]); s[2] = f2bs(a[2]); s[3] = f2bs(a[3]);
  s[4] = f2bs(b[0]); s[5] = f2bs(b[1]); s[6] = f2bs(b[2]); s[7] = f2bs(b[3]);
  *(short8*)((short*)out + i) = s;
}

// fused 4-weight conversion: z selects source; dst = base + z*1M elems
__global__ __launch_bounds__(256)
void conv_w4(const float* __restrict__ w0, const float* __restrict__ w1,
             const float* __restrict__ w2, const float* __restrict__ w3,
             bf16* __restrict__ out) {
  const float* src = (blockIdx.z == 0) ? w0 : (blockIdx.z == 1) ? w1
                   : (blockIdx.z == 2) ? w2 : w3;
  size_t i = ((size_t)blockIdx.x * 256 + threadIdx.x) * 8;
  f32x4 a = *(const f32x4*)(src + i);
  f32x4 b = *(const f32x4*)(src + i + 4);
  short8 s;
  s[0] = f2bs(a[0]); s[1] = f2bs(a[1]); s[2] = f2bs(a[2]); s[3] = f2bs(a[3]);
  s[4] = f2bs(b[0]); s[5] = f2bs(b[1]); s[6] = f2bs(b[2]); s[7] = f2bs(b[3]);
  *(short8*)((short*)out + (size_t)blockIdx.z * 1024 * 1024 + i) = s;
}

// ---------------- MFMA GEMM: C[M,1024] = A[M,1024] @ Wb[1024,1024]^T + bias -------------
// 128x128 tile, BK=64 (16 steps), 4 waves 2x2, DOUBLE-BUFFERED (2-phase):
//   prologue: stage(buf0, k=0); barrier
//   step t:   issue stage(buf^1, t+1)  ->  compute(buf)  ->  barrier; flip
// One vmcnt(0)+lgkm(0) drain per step (inside __syncthreads), overlapped with compute.
// aF32: 1 = A fp32 (T14 split: loads issued early, cvt+ds_write after compute).
// cMode: 0 = bf16 [m][n], 1 = fp32 [m][n], 2 = bf16 transposed vt[(m>>10)*1024+n][m&1023].
// cscale: epilogue scale (0.125 for Q projection: folds 1/sqrt(dk) into qh).
__global__ __launch_bounds__(256)
void gemm_mfma(const void* __restrict__ A, const bf16* __restrict__ Wb,
               const float* __restrict__ bias, void* __restrict__ C,
               int aF32, int cMode, float cscale)
{
  __shared__ short As[2][2][128 * 32];   // [buf][k-sub][row*32+kc]
  __shared__ short Bs[2][2][128 * 32];
  const int tid = threadIdx.x;
  const int lane = tid & 63;
  const int w = tid >> 6;
  const int l15 = lane & 15, quad = lane >> 4;
  const int wm = (w >> 1) * 64, wn = (w & 1) * 64;
  const int m0 = blockIdx.x * 128, n0 = blockIdx.y * 128;   // m-major dispatch

  // global_load_lds lane map: instr (sub,p) covers rows 32w+16p+(lane>>2), k-chunk
  // sub*32+(lane&3)*8; LDS offset = sub-base + w*2048 + p*1024 + lane*16  (derived exact)
  const int srow = (lane >> 2);
  const int skc  = (lane & 3) * 8;

  f32x4 au[4], av[4];   // fp32-A path in-flight regs (T14)

  auto stageA = [&](int buf, int k0) {
    const bf16* Ab = (const bf16*)A;
#pragma unroll
    for (int sub = 0; sub < 2; ++sub)
#pragma unroll
      for (int p = 0; p < 2; ++p) {
        int r = 32 * w + 16 * p + srow;
        __builtin_amdgcn_global_load_lds(
            (gas_u32p)(const void*)(Ab + (size_t)(m0 + r) * 1024 + k0 + sub * 32 + skc),
            (las_u32p)(void*)((char*)&As[buf][sub][0] + w * 2048 + p * 1024), 16, 0, 0);
      }
  };
  auto stageB = [&](int buf, int k0) {
#pragma unroll
    for (int sub = 0; sub < 2; ++sub)
#pragma unroll
      for (int p = 0; p < 2; ++p) {
        int r = 32 * w + 16 * p + srow;
        __builtin_amdgcn_global_load_lds(
            (gas_u32p)(const void*)(Wb + (size_t)(n0 + r) * 1024 + k0 + sub * 32 + skc),
            (las_u32p)(void*)((char*)&Bs[buf][sub][0] + w * 2048 + p * 1024), 16, 0, 0);
      }
  };
  auto loadAf = [&](int k0) {     // issue global loads only (early)
    const float* Af = (const float*)A;
#pragma unroll
    for (int p = 0; p < 4; ++p) {
      int c = p * 256 + tid;              // 0..1023 = 128 rows x 8 chunks
      int r = c >> 3, kc = (c & 7) * 8;
      const float* g = Af + (size_t)(m0 + r) * 1024 + k0 + kc;
      au[p] = *(const f32x4*)g;
      av[p] = *(const f32x4*)(g + 4);
    }
  };
  auto writeAf = [&](int buf) {   // cvt + LDS write (late, after compute)
#pragma unroll
    for (int p = 0; p < 4; ++p) {
      int c = p * 256 + tid;
      int r = c >> 3, kc = (c & 7) * 8;
      short8 s;
      s[0] = f2bs(au[p][0]); s[1] = f2bs(au[p][1]); s[2] = f2bs(au[p][2]); s[3] = f2bs(au[p][3]);
      s[4] = f2bs(av[p][0]); s[5] = f2bs(av[p][1]); s[6] = f2bs(av[p][2]); s[7] = f2bs(av[p][3]);
      *(short8*)&As[buf][kc >> 5][r * 32 + (kc & 31)] = s;
    }
  };

  f32x4 acc[4][4];
#pragma unroll
  for (int i = 0; i < 4; ++i)
#pragma unroll
    for (int j = 0; j < 4; ++j)
      acc[i][j] = (f32x4){0.f, 0.f, 0.f, 0.f};

  // prologue: fill buf0
  if (aF32) { loadAf(0); writeAf(0); }
  else       stageA(0, 0);
  stageB(0, 0);
  __syncthreads();   // drains vmcnt+lgkm: buf0 ready

#pragma unroll 2
  for (int k0 = 0; k0 < 1024; k0 += 64) {
    const int cur = (k0 >> 6) & 1;
    const int nxt = cur ^ 1;
    const bool pf = (k0 + 64) < 1024;

    if (pf) {                       // issue next-tile loads BEFORE compute
      if (aF32) loadAf(k0 + 64);
      else      stageA(nxt, k0 + 64);
      stageB(nxt, k0 + 64);
    }

#pragma unroll
    for (int kk = 0; kk < 2; ++kk) {
      short8 af[4], bfv[4];
#pragma unroll
      for (int t = 0; t < 4; ++t) {
        af[t]  = *(short8*)&As[cur][kk][(wm + t * 16 + l15) * 32 + quad * 8];
        bfv[t] = *(short8*)&Bs[cur][kk][(wn + t * 16 + l15) * 32 + quad * 8];
      }
#pragma unroll
      for (int mt = 0; mt < 4; ++mt)
#pragma unroll
        for (int nt = 0; nt < 4; ++nt)
          acc[mt][nt] = __builtin_amdgcn_mfma_f32_16x16x32_bf16(af[mt], bfv[nt], acc[mt][nt], 0, 0, 0);
    }

    if (pf && aF32) writeAf(nxt);   // loads had the whole compute phase to land

    __syncthreads();   // one drain per step: next buf ready AND cur safe to overwrite
  }

  // epilogue: C/D layout col=lane&15, row=quad*4+reg
  if (cMode == 2) {
    bf16* vt = (bf16*)C;
    const int bidx = m0 >> 10;
    const int sbase = (m0 & 1023) + wm;
#pragma unroll
    for (int nt = 0; nt < 4; ++nt) {
      int n = n0 + wn + nt * 16 + l15;
      float bv = bias[n];
#pragma unroll
      for (int mt = 0; mt < 4; ++mt) {
        int s = sbase + mt * 16 + quad * 4;
        short4_t pk;
#pragma unroll
        for (int r = 0; r < 4; ++r) pk[r] = f2bs((acc[mt][nt][r] + bv) * cscale);
        *(short4_t*)((short*)vt + ((size_t)bidx * 1024 + n) * 1024 + s) = pk;
      }
    }
  } else {
#pragma unroll
    for (int nt = 0; nt < 4; ++nt) {
      int col = n0 + wn + nt * 16 + l15;
      float bv = bias[col];
#pragma unroll
      for (int mt = 0; mt < 4; ++mt)
#pragma unroll
        for (int r = 0; r < 4; ++r) {
          int row = m0 + wm + mt * 16 + quad * 4 + r;
          float val = (acc[mt][nt][r] + bv) * cscale;
          if (cMode == 1) ((float*)C)[(size_t)row * 1024 + col] = val;
          else ((bf16*)C)[(size_t)row * 1024 + col] = __float2bfloat16(val);
        }
    }
  }
}

// ---------------- MFMA flash attention: shared-LDS K/V, transposed-S ----------------
// Block = (64-q-tile, head, batch); wave w owns q rows q0+w*16..+15.
// K tile and V^T tile staged once per block via global_load_lds (coalesced, zero VALU);
// frags via ds_read_b128. S^T = mfma(K,Q) -> lane holds 16 kv of q-row l15; softmax =
// tree reg-reduce + 2 shfl; defer-max (T13, THR=8) skips O-rescale on most tiles;
// P -> A-frag via wave-private LDS strip; PV B-frags from Vs. Q pre-scaled by 1/8.
__global__ __launch_bounds__(256)
void attn_mfma(const bf16* __restrict__ QH, const bf16* __restrict__ KH,
               const bf16* __restrict__ VT, bf16* __restrict__ AO)
{
  __shared__ short Ks[2][64 * 32];   // sub ks: dk in [32ks,32ks+32)
  __shared__ short Vs[2][64 * 32];   // sub ks: s_local in [32ks,32ks+32), rows dv
  __shared__ short Ps[4][16 * 72];   // per-wave strip
  const int tid = threadIdx.x;
  const int lane = tid & 63;
  const int w = tid >> 6;
  const int l15 = lane & 15, quad = lane >> 4;
  const int q0 = blockIdx.x * 64;
  const int h = blockIdx.y, b = blockIdx.z;
  const size_t base = ((size_t)b * S_) * D_MODEL_ + (size_t)h * DK_;   // QH/KH/AO
  const size_t vtb  = (((size_t)b * NH_ + h) * DK_) * (size_t)S_;      // VT rows (dv)
  const float NEG = -1e30f;
  short* myPs = Ps[w];

  // staging lane map: rows 16w+(lane>>2), chunk (lane&3)*8; LDS = sub-base + w*1024 + lane*16
  const int srow = 16 * w + (lane >> 2);
  const int skc  = (lane & 3) * 8;

  // Q A-frags (once per block; read before any AO store - ao aliases qh)
  short8 qa[2];
#pragma unroll
  for (int ks = 0; ks < 2; ++ks)
    qa[ks] = *(const short8*)((const short*)QH + base + (size_t)(q0 + w * 16 + l15) * D_MODEL_ + ks * 32 + quad * 8);

  float mi = NEG, li = 0.f;
  f32x4 oacc[4];
#pragma unroll
  for (int nt = 0; nt < 4; ++nt) oacc[nt] = (f32x4){0.f, 0.f, 0.f, 0.f};

  for (int j0 = 0; j0 < S_; j0 += 64) {
    __syncthreads();   // protect Ks/Vs from previous iteration's readers
#pragma unroll
    for (int sub = 0; sub < 2; ++sub) {
      __builtin_amdgcn_global_load_lds(
          (gas_u32p)(const void*)((const short*)KH + base + (size_t)(j0 + srow) * D_MODEL_ + sub * 32 + skc),
          (las_u32p)(void*)((char*)&Ks[sub][0] + w * 1024), 16, 0, 0);
      __builtin_amdgcn_global_load_lds(
          (gas_u32p)(const void*)((const short*)VT + vtb + (size_t)srow * S_ + j0 + sub * 32 + skc),
          (las_u32p)(void*)((char*)&Vs[sub][0] + w * 1024), 16, 0, 0);
    }
    __syncthreads();   // drains vmcnt

    // frag reads (b128 from LDS, shared across waves)
    short8 kb[4][2], vb[4][2];
#pragma unroll
    for (int nt = 0; nt < 4; ++nt)
#pragma unroll
      for (int ks = 0; ks < 2; ++ks) {
        kb[nt][ks] = *(short8*)&Ks[ks][(nt * 16 + l15) * 32 + quad * 8];
        vb[nt][ks] = *(short8*)&Vs[ks][(nt * 16 + l15) * 32 + quad * 8];
      }

    // S^T: A=K (m=kv), B=Q (n=q) -> lane: q=l15, kv rows nt*16+quad*4+r
    f32x4 sacc[4];
#pragma unroll
    for (int nt = 0; nt < 4; ++nt) sacc[nt] = (f32x4){0.f, 0.f, 0.f, 0.f};
    __builtin_amdgcn_s_setprio(1);
#pragma unroll
    for (int nt = 0; nt < 4; ++nt)
#pragma unroll
      for (int ks = 0; ks < 2; ++ks)
        sacc[nt] = __builtin_amdgcn_mfma_f32_16x16x32_bf16(kb[nt][ks], qa[ks], sacc[nt], 0, 0, 0);
    __builtin_amdgcn_s_setprio(0);

    // softmax over 16 in-register kv values of q-row l15 (+2 shfl across quads).
    // Q pre-scaled by 1/8 in GEMM epilogue; mask (scaled x)==0 <=> scores==0 (exact pow2).
    float p[4][4];
#pragma unroll
    for (int nt = 0; nt < 4; ++nt)
#pragma unroll
      for (int r = 0; r < 4; ++r) {
        float x = sacc[nt][r];
        if (x == 0.0f) x = NEG;                  // faithful scalar-equality mask
        p[nt][r] = x;
      }
    // tree max (depth 4)
    float mm[4];
#pragma unroll
    for (int nt = 0; nt < 4; ++nt)
      mm[nt] = fmaxf(fmaxf(p[nt][0], p[nt][1]), fmaxf(p[nt][2], p[nt][3]));
    float rm = fmaxf(fmaxf(mm[0], mm[1]), fmaxf(mm[2], mm[3]));
    rm = fmaxf(rm, __shfl_xor(rm, 16, 64));
    rm = fmaxf(rm, __shfl_xor(rm, 32, 64));

    // defer-max (T13): if no row's max grew by >8, keep old max -> skip rescale entirely.
    // P then bounded by e^8 (~3e3), safe in bf16/f32; math identical after final /li.
    const bool skip = __all(rm <= mi + 8.0f);
    const float nm = skip ? mi : fmaxf(mi, rm);

    float psum[4];
#pragma unroll
    for (int nt = 0; nt < 4; ++nt) {
      float e0 = __expf(p[nt][0] - nm), e1 = __expf(p[nt][1] - nm);
      float e2 = __expf(p[nt][2] - nm), e3 = __expf(p[nt][3] - nm);
      p[nt][0] = e0; p[nt][1] = e1; p[nt][2] = e2; p[nt][3] = e3;
      psum[nt] = (e0 + e1) + (e2 + e3);
    }
    float ps = (psum[0] + psum[1]) + (psum[2] + psum[3]);
    ps += __shfl_xor(ps, 16, 64);
    ps += __shfl_xor(ps, 32, 64);

    if (skip) {
      li += ps;                       // mi unchanged, no O-rescale
    } else {
      float alpha = __expf(mi - nm);  // first tile: exp(-inf)=0 zeroes O correctly
      li = li * alpha + ps;
      // rescale O: O rows q_local=quad*4+r; alpha lives at lane l15'=q_local
      float ar[4];
#pragma unroll
      for (int r = 0; r < 4; ++r) ar[r] = __shfl(alpha, quad * 4 + r, 64);
#pragma unroll
      for (int nt = 0; nt < 4; ++nt)
#pragma unroll
        for (int r = 0; r < 4; ++r) oacc[nt][r] *= ar[r];
    }
    mi = nm;

    // P -> wave-private LDS strip [q=l15][kv]
#pragma unroll
    for (int nt = 0; nt < 4; ++nt) {
      short4_t pk;
#pragma unroll
      for (int r = 0; r < 4; ++r) pk[r] = f2bs(p[nt][r]);
      *(short4_t*)&myPs[l15 * 72 + nt * 16 + quad * 4] = pk;
    }

    __threadfence_block();   // order Ps writes before same-wave b128 reads

    short8 pa[2];
#pragma unroll
    for (int ks = 0; ks < 2; ++ks)
      pa[ks] = *(short8*)&myPs[l15 * 72 + ks * 32 + quad * 8];
    __builtin_amdgcn_s_setprio(1);
#pragma unroll
    for (int nt = 0; nt < 4; ++nt)
#pragma unroll
      for (int ks = 0; ks < 2; ++ks)
        oacc[nt] = __builtin_amdgcn_mfma_f32_16x16x32_bf16(pa[ks], vb[nt][ks], oacc[nt], 0, 0, 0);
    __builtin_amdgcn_s_setprio(0);
  }

  // epilogue: O rows q_local=quad*4+r, cols dv=nt*16+l15; li at lane l15'=q_local
  float lr[4];
#pragma unroll
  for (int r = 0; r < 4; ++r) lr[r] = __shfl(li, quad * 4 + r, 64);
#pragma unroll
  for (int r = 0; r < 4; ++r) {
    float inv = (lr[r] > 0.f) ? 1.0f / lr[r] : 0.f;
    int q = q0 + w * 16 + quad * 4 + r;
#pragma unroll
    for (int nt = 0; nt < 4; ++nt)
      AO[base + (size_t)q * D_MODEL_ + nt * 16 + l15] = __float2bfloat16(oacc[nt][r] * inv);
  }
}

extern "C" void kernel_launch(void* const* d_in, const int* in_sizes, int n_in,
                              void* d_out, int out_size, void* d_ws, size_t ws_size,
                              hipStream_t stream) {
  (void)in_sizes; (void)n_in; (void)out_size; (void)ws_size;
  const float* q  = (const float*)d_in[0];
  const float* k  = (const float*)d_in[1];
  const float* v  = (const float*)d_in[2];
  const float* Wq = (const float*)d_in[3];
  const float* bq = (const float*)d_in[4];
  const float* Wk = (const float*)d_in[5];
  const float* bk = (const float*)d_in[6];
  const float* Wv = (const float*)d_in[7];
  const float* bv = (const float*)d_in[8];
  const float* Wf = (const float*)d_in[9];
  const float* bF = (const float*)d_in[10];

  const size_t MB = (size_t)1024 * 1024;
  char* ws = (char*)d_ws;
  bf16* wb4 = (bf16*)(ws);                 // [0,8): Wq|Wk|Wv|Wf bf16
  bf16* wqb = wb4;
  bf16* wkb = (bf16*)(ws + 2 * MB);
  bf16* wvb = (bf16*)(ws + 4 * MB);
  bf16* wfb = (bf16*)(ws + 6 * MB);
  bf16* inb = (bf16*)(ws + 8 * MB);        // [8,24) input conv slot / ao copy
  bf16* vt  = (bf16*)(ws + 16 * MB);       // [16,32) transposed V
  bf16* qh  = (bf16*)d_out;                // d_out [0,16): qh -> ao in-place
  bf16* kh  = (bf16*)((char*)d_out + 16 * MB);

  dim3 blk(256);
  dim3 igrid(4096);                         // 8M elems
  dim3 ggrid(M_ / 128, D_MODEL_ / 128);     // (64, 8) m-major

  conv_w4<<<dim3(512, 1, 4), blk, 0, stream>>>(Wq, Wk, Wv, Wf, wb4);

  conv_f32_bf16<<<igrid, blk, 0, stream>>>(q, inb);
  gemm_mfma<<<ggrid, blk, 0, stream>>>(inb, wqb, bq, qh, 0, 0, 0.125f);  // Q pre-scaled
  conv_f32_bf16<<<igrid, blk, 0, stream>>>(k, inb);
  gemm_mfma<<<ggrid, blk, 0, stream>>>(inb, wkb, bk, kh, 0, 0, 1.0f);
  gemm_mfma<<<ggrid, blk, 0, stream>>>(v, wvb, bv, vt, 1, 2, 1.0f);      // fp32 A, vt store

  attn_mfma<<<dim3(S_ / 64, NH_, B_), blk, 0, stream>>>(qh, kh, vt, qh); // ao over qh

  hipMemcpyAsync(inb, d_out, 16 * MB, hipMemcpyDeviceToDevice, stream);  // park ao
  gemm_mfma<<<ggrid, blk, 0, stream>>>(inb, wfb, bF, d_out, 0, 1, 1.0f);
}

// Round 2
// 330.349 us; speedup vs baseline: 1.0937x; 1.0937x over previous
//
#include <hip/hip_runtime.h>
#include <hip/hip_bf16.h>

// MultiHeadAttentionLayer: B=8, S=1024, D_MODEL=1024, H=16, DK=64. fp32 in/out.
// Round 8: (1) Q/K/V projections fused into ONE dispatch (grid z=3, fp32-A T14 reg
// staging) - removes 2 conv launches, TLP 2 -> ~5 blocks/CU. (2) final GEMM 128x64
// tiles -> 1024 blocks = 4/CU. (3) T2 XOR swizzle on ALL staged LDS tiles (rule-21
// pattern: linear gload_lds dest + pre-swizzled per-lane GLOBAL source + swizzled
// ds_read slot) - kills the 8-way bank conflict (attn: 1.15e7 conflict cycles =
// ~19us/dispatch). (4) ws_size>=40MB -> attn writes AO to own buffer, no park memcpy.
// Buffers: ws[0,8)=W bf16 x4, ws[8,24)=vt (later ao park), ws[24,40)=ao if room;
// d_out[0,16)=qh, d_out[16,32)=kh.

#define D_MODEL_ 1024
#define NH_ 16
#define DK_ 64
#define B_ 8
#define S_ 1024
#define M_ (B_ * S_)   // 8192 rows

typedef __hip_bfloat16 bf16;
typedef __attribute__((ext_vector_type(8))) short short8;   // 8 bf16 = 4 VGPRs (MFMA A/B frag)
typedef __attribute__((ext_vector_type(4))) short short4_t; // 4 bf16 = 8B
typedef __attribute__((ext_vector_type(4))) float f32x4;    // MFMA C/D frag

typedef const __attribute__((address_space(1))) unsigned int* gas_u32p;
typedef __attribute__((address_space(3))) unsigned int* las_u32p;

__device__ __forceinline__ short f2bs(float x) {
  bf16 h = __float2bfloat16(x);
  return *reinterpret_cast<short*>(&h);
}

// fused 4-weight conversion: z selects source; dst = base + z*1M elems
__global__ __launch_bounds__(256)
void conv_w4(const float* __restrict__ w0, const float* __restrict__ w1,
             const float* __restrict__ w2, const float* __restrict__ w3,
             bf16* __restrict__ out) {
  const float* src = (blockIdx.z == 0) ? w0 : (blockIdx.z == 1) ? w1
                   : (blockIdx.z == 2) ? w2 : w3;
  size_t i = ((size_t)blockIdx.x * 256 + threadIdx.x) * 8;
  f32x4 a = *(const f32x4*)(src + i);
  f32x4 b = *(const f32x4*)(src + i + 4);
  short8 s;
  s[0] = f2bs(a[0]); s[1] = f2bs(a[1]); s[2] = f2bs(a[2]); s[3] = f2bs(a[3]);
  s[4] = f2bs(b[0]); s[5] = f2bs(b[1]); s[6] = f2bs(b[2]); s[7] = f2bs(b[3]);
  *(short8*)((short*)out + (size_t)blockIdx.z * 1024 * 1024 + i) = s;
}

// ---------------- MFMA GEMM body: C[M,1024] = A[M,1024] @ Wb[1024,1024]^T + bias --------
// 128xBN tile, BK=64 (16 steps), 4 waves, single-buffered (2 barriers/step; co-resident
// blocks hide stage latency). LDS tiles XOR-swizzled: slot' = slot ^ ((row>>1)&3).
// Staging keeps LINEAR gload_lds dest; the swizzle is applied by permuting the per-lane
// GLOBAL source chunk (valid: (row>>1)&3 == (lane>>3)&3 for every stage map here).
// Reads apply slot ^= (l15>>1)&3 (row base is a multiple of 16 -> factor = (l15>>1)&3).
// AF32: A is fp32, T14 reg staging (loads for step t+1 issued under compute of t).
// cMode: 0 = bf16 [m][n], 1 = fp32 [m][n], 2 = bf16 transposed vt[(m>>10)*1024+n][m&1023].
template<int BN, int AF32>
__device__ __forceinline__ void gemm_body(const void* __restrict__ A,
                                          const bf16* __restrict__ Wb,
                                          const float* __restrict__ bias,
                                          void* __restrict__ C,
                                          int cMode, float cscale, int m0, int n0)
{
  __shared__ short As[2][128 * 32];    // [k-sub][row*32 + slot*8]
  __shared__ short Bs[2][BN * 32];
  const int tid = threadIdx.x;
  const int lane = tid & 63;
  const int w = tid >> 6;
  const int l15 = lane & 15, quad = lane >> 4;
  const int wm = (w >> 1) * 64, wn = (w & 1) * (BN / 2);
  const int srow = lane >> 2;
  const int sslot = ((lane & 3) ^ ((lane >> 3) & 3)) * 8;  // pre-swizzled global chunk
  const int rsl = (quad ^ ((l15 >> 1) & 3)) * 8;           // swizzled read slot

  f32x4 au[4], av[4];   // AF32 in-flight regs (T14)
  auto loadAf = [&](int k0) {
    const float* Af = (const float*)A;
#pragma unroll
    for (int p = 0; p < 4; ++p) {
      int c = p * 256 + tid;              // 0..1023 = 128 rows x 8 chunks
      int r = c >> 3, kc = (c & 7) * 8;
      const float* g = Af + (size_t)(m0 + r) * 1024 + k0 + kc;
      au[p] = *(const f32x4*)g;
      av[p] = *(const f32x4*)(g + 4);
    }
  };
  auto writeAf = [&]() {
#pragma unroll
    for (int p = 0; p < 4; ++p) {
      int c = p * 256 + tid;
      int r = c >> 3, kc = (c & 7) * 8;
      int s = (c & 3) ^ ((r >> 1) & 3);   // swizzled dest slot
      short8 sv;
      sv[0] = f2bs(au[p][0]); sv[1] = f2bs(au[p][1]); sv[2] = f2bs(au[p][2]); sv[3] = f2bs(au[p][3]);
      sv[4] = f2bs(av[p][0]); sv[5] = f2bs(av[p][1]); sv[6] = f2bs(av[p][2]); sv[7] = f2bs(av[p][3]);
      *(short8*)&As[kc >> 5][r * 32 + s * 8] = sv;
    }
  };

  f32x4 acc[4][BN / 32];
#pragma unroll
  for (int i = 0; i < 4; ++i)
#pragma unroll
    for (int j = 0; j < BN / 32; ++j)
      acc[i][j] = (f32x4){0.f, 0.f, 0.f, 0.f};

  if (AF32) loadAf(0);

  for (int k0 = 0; k0 < 1024; k0 += 64) {
    __syncthreads();   // protect As/Bs from previous step's frag reads
    if (AF32) {
      writeAf();
    } else {
      const bf16* Ab = (const bf16*)A;
#pragma unroll
      for (int sub = 0; sub < 2; ++sub)
#pragma unroll
        for (int p = 0; p < 2; ++p) {
          int r = 32 * w + 16 * p + srow;
          __builtin_amdgcn_global_load_lds(
              (gas_u32p)(const void*)(Ab + (size_t)(m0 + r) * 1024 + k0 + sub * 32 + sslot),
              (las_u32p)(void*)((char*)&As[sub][0] + w * 2048 + p * 1024), 16, 0, 0);
        }
    }
#pragma unroll
    for (int sub = 0; sub < 2; ++sub)
#pragma unroll
      for (int p = 0; p < BN / 64; ++p) {
        int r = (BN / 4) * w + 16 * p + srow;
        __builtin_amdgcn_global_load_lds(
            (gas_u32p)(const void*)(Wb + (size_t)(n0 + r) * 1024 + k0 + sub * 32 + sslot),
            (las_u32p)(void*)((char*)&Bs[sub][0] + w * (BN / 4) * 64 + p * 1024), 16, 0, 0);
      }
    __syncthreads();   // drains vmcnt + lgkm: tile ready

    if (AF32 && k0 + 64 < 1024) loadAf(k0 + 64);   // next-step loads fly under compute

#pragma unroll
    for (int kk = 0; kk < 2; ++kk) {
      short8 af[4], bfv[BN / 32];
#pragma unroll
      for (int t = 0; t < 4; ++t)
        af[t]  = *(short8*)&As[kk][(wm + t * 16 + l15) * 32 + rsl];
#pragma unroll
      for (int t = 0; t < BN / 32; ++t)
        bfv[t] = *(short8*)&Bs[kk][(wn + t * 16 + l15) * 32 + rsl];
#pragma unroll
      for (int mt = 0; mt < 4; ++mt)
#pragma unroll
        for (int nt = 0; nt < BN / 32; ++nt)
          acc[mt][nt] = __builtin_amdgcn_mfma_f32_16x16x32_bf16(af[mt], bfv[nt], acc[mt][nt], 0, 0, 0);
    }
  }

  // epilogue: C/D layout col=lane&15, row=quad*4+reg
  if (cMode == 2) {
    bf16* vt = (bf16*)C;
    const int bidx = m0 >> 10;
    const int sbase = (m0 & 1023) + wm;
#pragma unroll
    for (int nt = 0; nt < BN / 32; ++nt) {
      int n = n0 + wn + nt * 16 + l15;
      float bv = bias[n];
#pragma unroll
      for (int mt = 0; mt < 4; ++mt) {
        int s = sbase + mt * 16 + quad * 4;
        short4_t pk;
#pragma unroll
        for (int r = 0; r < 4; ++r) pk[r] = f2bs((acc[mt][nt][r] + bv) * cscale);
        *(short4_t*)((short*)vt + ((size_t)bidx * 1024 + n) * 1024 + s) = pk;
      }
    }
  } else {
#pragma unroll
    for (int nt = 0; nt < BN / 32; ++nt) {
      int col = n0 + wn + nt * 16 + l15;
      float bv = bias[col];
#pragma unroll
      for (int mt = 0; mt < 4; ++mt)
#pragma unroll
        for (int r = 0; r < 4; ++r) {
          int row = m0 + wm + mt * 16 + quad * 4 + r;
          float val = (acc[mt][nt][r] + bv) * cscale;
          if (cMode == 1) ((float*)C)[(size_t)row * 1024 + col] = val;
          else ((bf16*)C)[(size_t)row * 1024 + col] = __float2bfloat16(val);
        }
    }
  }
}

// fused Q/K/V projection: z selects (A, W, bias, C, cMode, cscale). 1536 blocks.
__global__ __launch_bounds__(256)
void gemm_proj(const float* __restrict__ q, const float* __restrict__ k,
               const float* __restrict__ v, const bf16* __restrict__ wq,
               const bf16* __restrict__ wk, const bf16* __restrict__ wv,
               const float* __restrict__ bq, const float* __restrict__ bk,
               const float* __restrict__ bv, void* __restrict__ cq,
               void* __restrict__ ck, void* __restrict__ cv)
{
  const int z = blockIdx.z;
  const float* A = (z == 0) ? q : (z == 1) ? k : v;
  const bf16* W  = (z == 0) ? wq : (z == 1) ? wk : wv;
  const float* bb = (z == 0) ? bq : (z == 1) ? bk : bv;
  void* C = (z == 0) ? cq : (z == 1) ? ck : cv;
  int cMode = (z == 2) ? 2 : 0;
  float cscale = (z == 0) ? 0.125f : 1.0f;   // fold 1/sqrt(dk) into qh
  gemm_body<128, 1>(A, W, bb, C, cMode, cscale, blockIdx.x * 128, blockIdx.y * 128);
}

// final projection: 128x64 tiles -> 1024 blocks (4/CU), bf16 A via gload_lds
__global__ __launch_bounds__(256)
void gemm_final(const bf16* __restrict__ A, const bf16* __restrict__ W,
                const float* __restrict__ bias, void* __restrict__ C)
{
  gemm_body<64, 0>(A, W, bias, C, 1, 1.0f, blockIdx.x * 128, blockIdx.y * 64);
}

// ---------------- MFMA flash attention: shared-LDS K/V, transposed-S ----------------
// Block = (64-q-tile, head, batch); wave w owns q rows q0+w*16..+15.
// K tile and V^T tile staged once per block via global_load_lds with pre-swizzled
// source (T2); frag reads use swizzled slot -> 2-way (free) instead of 8-way conflicts.
// S^T = mfma(K,Q); softmax tree reg-reduce + 2 shfl; defer-max (T13, THR=8);
// P -> A-frag via wave-private LDS strip; PV B-frags from Vs. Q pre-scaled by 1/8.
__global__ __launch_bounds__(256)
void attn_mfma(const bf16* __restrict__ QH, const bf16* __restrict__ KH,
               const bf16* __restrict__ VT, bf16* __restrict__ AO)
{
  __shared__ short Ks[2][64 * 32];   // sub ks: dk in [32ks,32ks+32)
  __shared__ short Vs[2][64 * 32];   // sub ks: s_local in [32ks,32ks+32), rows dv
  __shared__ short Ps[4][16 * 72];   // per-wave strip (stride 144B: conflict-free)
  const int tid = threadIdx.x;
  const int lane = tid & 63;
  const int w = tid >> 6;
  const int l15 = lane & 15, quad = lane >> 4;
  const int q0 = blockIdx.x * 64;
  const int h = blockIdx.y, b = blockIdx.z;
  const size_t base = ((size_t)b * S_) * D_MODEL_ + (size_t)h * DK_;   // QH/KH/AO
  const size_t vtb  = (((size_t)b * NH_ + h) * DK_) * (size_t)S_;      // VT rows (dv)
  const float NEG = -1e30f;
  short* myPs = Ps[w];

  // staging: rows 16w+(lane>>2); source chunk pre-swizzled ((row>>1)&3 == (lane>>3)&3)
  const int srow = 16 * w + (lane >> 2);
  const int sslot = ((lane & 3) ^ ((lane >> 3) & 3)) * 8;
  const int rsl = (quad ^ ((l15 >> 1) & 3)) * 8;   // swizzled read slot

  // Q A-frags (once per block; read before any AO store - ao may alias qh)
  short8 qa[2];
#pragma unroll
  for (int ks = 0; ks < 2; ++ks)
    qa[ks] = *(const short8*)((const short*)QH + base + (size_t)(q0 + w * 16 + l15) * D_MODEL_ + ks * 32 + quad * 8);

  float mi = NEG, li = 0.f;
  f32x4 oacc[4];
#pragma unroll
  for (int nt = 0; nt < 4; ++nt) oacc[nt] = (f32x4){0.f, 0.f, 0.f, 0.f};

  for (int j0 = 0; j0 < S_; j0 += 64) {
    __syncthreads();   // protect Ks/Vs from previous iteration's readers
#pragma unroll
    for (int sub = 0; sub < 2; ++sub) {
      __builtin_amdgcn_global_load_lds(
          (gas_u32p)(const void*)((const short*)KH + base + (size_t)(j0 + srow) * D_MODEL_ + sub * 32 + sslot),
          (las_u32p)(void*)((char*)&Ks[sub][0] + w * 1024), 16, 0, 0);
      __builtin_amdgcn_global_load_lds(
          (gas_u32p)(const void*)((const short*)VT + vtb + (size_t)srow * S_ + j0 + sub * 32 + sslot),
          (las_u32p)(void*)((char*)&Vs[sub][0] + w * 1024), 16, 0, 0);
    }
    __syncthreads();   // drains vmcnt

    // frag reads (b128 from LDS, swizzled slot -> conflict-free)
    short8 kb[4][2], vb[4][2];
#pragma unroll
    for (int nt = 0; nt < 4; ++nt)
#pragma unroll
      for (int ks = 0; ks < 2; ++ks) {
        kb[nt][ks] = *(short8*)&Ks[ks][(nt * 16 + l15) * 32 + rsl];
        vb[nt][ks] = *(short8*)&Vs[ks][(nt * 16 + l15) * 32 + rsl];
      }

    // S^T: A=K (m=kv), B=Q (n=q) -> lane: q=l15, kv rows nt*16+quad*4+r
    f32x4 sacc[4];
#pragma unroll
    for (int nt = 0; nt < 4; ++nt) sacc[nt] = (f32x4){0.f, 0.f, 0.f, 0.f};
    __builtin_amdgcn_s_setprio(1);
#pragma unroll
    for (int nt = 0; nt < 4; ++nt)
#pragma unroll
      for (int ks = 0; ks < 2; ++ks)
        sacc[nt] = __builtin_amdgcn_mfma_f32_16x16x32_bf16(kb[nt][ks], qa[ks], sacc[nt], 0, 0, 0);
    __builtin_amdgcn_s_setprio(0);

    // softmax over 16 in-register kv values of q-row l15 (+2 shfl across quads).
    // Q pre-scaled by 1/8 in GEMM epilogue; mask (scaled x)==0 <=> scores==0 (exact pow2).
    float p[4][4];
#pragma unroll
    for (int nt = 0; nt < 4; ++nt)
#pragma unroll
      for (int r = 0; r < 4; ++r) {
        float x = sacc[nt][r];
        if (x == 0.0f) x = NEG;                  // faithful scalar-equality mask
        p[nt][r] = x;
      }
    // tree max (depth 4)
    float mm[4];
#pragma unroll
    for (int nt = 0; nt < 4; ++nt)
      mm[nt] = fmaxf(fmaxf(p[nt][0], p[nt][1]), fmaxf(p[nt][2], p[nt][3]));
    float rm = fmaxf(fmaxf(mm[0], mm[1]), fmaxf(mm[2], mm[3]));
    rm = fmaxf(rm, __shfl_xor(rm, 16, 64));
    rm = fmaxf(rm, __shfl_xor(rm, 32, 64));

    // defer-max (T13): if no row's max grew by >8, keep old max -> skip rescale entirely.
    const bool skip = __all(rm <= mi + 8.0f);
    const float nm = skip ? mi : fmaxf(mi, rm);

    float psum[4];
#pragma unroll
    for (int nt = 0; nt < 4; ++nt) {
      float e0 = __expf(p[nt][0] - nm), e1 = __expf(p[nt][1] - nm);
      float e2 = __expf(p[nt][2] - nm), e3 = __expf(p[nt][3] - nm);
      p[nt][0] = e0; p[nt][1] = e1; p[nt][2] = e2; p[nt][3] = e3;
      psum[nt] = (e0 + e1) + (e2 + e3);
    }
    float ps = (psum[0] + psum[1]) + (psum[2] + psum[3]);
    ps += __shfl_xor(ps, 16, 64);
    ps += __shfl_xor(ps, 32, 64);

    if (skip) {
      li += ps;                       // mi unchanged, no O-rescale
    } else {
      float alpha = __expf(mi - nm);  // first tile: exp(-inf)=0 zeroes O correctly
      li = li * alpha + ps;
      float ar[4];
#pragma unroll
      for (int r = 0; r < 4; ++r) ar[r] = __shfl(alpha, quad * 4 + r, 64);
#pragma unroll
      for (int nt = 0; nt < 4; ++nt)
#pragma unroll
        for (int r = 0; r < 4; ++r) oacc[nt][r] *= ar[r];
    }
    mi = nm;

    // P -> wave-private LDS strip [q=l15][kv]
#pragma unroll
    for (int nt = 0; nt < 4; ++nt) {
      short4_t pk;
#pragma unroll
      for (int r = 0; r < 4; ++r) pk[r] = f2bs(p[nt][r]);
      *(short4_t*)&myPs[l15 * 72 + nt * 16 + quad * 4] = pk;
    }

    __threadfence_block();   // order Ps writes before same-wave b128 reads

    short8 pa[2];
#pragma unroll
    for (int ks = 0; ks < 2; ++ks)
      pa[ks] = *(short8*)&myPs[l15 * 72 + ks * 32 + quad * 8];
    __builtin_amdgcn_s_setprio(1);
#pragma unroll
    for (int nt = 0; nt < 4; ++nt)
#pragma unroll
      for (int ks = 0; ks < 2; ++ks)
        oacc[nt] = __builtin_amdgcn_mfma_f32_16x16x32_bf16(pa[ks], vb[nt][ks], oacc[nt], 0, 0, 0);
    __builtin_amdgcn_s_setprio(0);
  }

  // epilogue: O rows q_local=quad*4+r, cols dv=nt*16+l15; li at lane l15'=q_local
  float lr[4];
#pragma unroll
  for (int r = 0; r < 4; ++r) lr[r] = __shfl(li, quad * 4 + r, 64);
#pragma unroll
  for (int r = 0; r < 4; ++r) {
    float inv = (lr[r] > 0.f) ? 1.0f / lr[r] : 0.f;
    int q = q0 + w * 16 + quad * 4 + r;
#pragma unroll
    for (int nt = 0; nt < 4; ++nt)
      AO[base + (size_t)q * D_MODEL_ + nt * 16 + l15] = __float2bfloat16(oacc[nt][r] * inv);
  }
}

extern "C" void kernel_launch(void* const* d_in, const int* in_sizes, int n_in,
                              void* d_out, int out_size, void* d_ws, size_t ws_size,
                              hipStream_t stream) {
  (void)in_sizes; (void)n_in; (void)out_size;
  const float* q  = (const float*)d_in[0];
  const float* k  = (const float*)d_in[1];
  const float* v  = (const float*)d_in[2];
  const float* Wq = (const float*)d_in[3];
  const float* bq = (const float*)d_in[4];
  const float* Wk = (const float*)d_in[5];
  const float* bk = (const float*)d_in[6];
  const float* Wv = (const float*)d_in[7];
  const float* bv = (const float*)d_in[8];
  const float* Wf = (const float*)d_in[9];
  const float* bF = (const float*)d_in[10];

  const size_t MB = (size_t)1024 * 1024;
  char* ws = (char*)d_ws;
  bf16* wqb = (bf16*)(ws);                 // [0,8): Wq|Wk|Wv|Wf bf16
  bf16* wkb = (bf16*)(ws + 2 * MB);
  bf16* wvb = (bf16*)(ws + 4 * MB);
  bf16* wfb = (bf16*)(ws + 6 * MB);
  bf16* vt  = (bf16*)(ws + 8 * MB);        // [8,24) transposed V (later ao park)
  bf16* qh  = (bf16*)d_out;                // d_out [0,16): qh
  bf16* kh  = (bf16*)((char*)d_out + 16 * MB);

  const bool bigws = ws_size >= (size_t)40 * MB;
  bf16* aob = bigws ? (bf16*)(ws + 24 * MB) : qh;    // attn output target
  bf16* fin = bigws ? aob : (bf16*)(ws + 8 * MB);    // final-GEMM A source

  dim3 blk(256);

  conv_w4<<<dim3(512, 1, 4), blk, 0, stream>>>(Wq, Wk, Wv, Wf, wqb);

  gemm_proj<<<dim3(M_ / 128, D_MODEL_ / 128, 3), blk, 0, stream>>>(
      q, k, v, wqb, wkb, wvb, bq, bk, bv, qh, kh, vt);

  attn_mfma<<<dim3(S_ / 64, NH_, B_), blk, 0, stream>>>(qh, kh, vt, aob);

  if (!bigws)   // park ao (qh region) into the dead vt slot
    hipMemcpyAsync(ws + 8 * MB, d_out, 16 * MB, hipMemcpyDeviceToDevice, stream);

  gemm_final<<<dim3(M_ / 128, D_MODEL_ / 64), blk, 0, stream>>>(fin, wfb, bF, d_out);
}